// Round 1
// baseline (74.248 us; speedup 1.0000x reference)
//
#include <hip/hip_runtime.h>
#include <math.h>

// MaxYager2d: out[b,f,si,sj] = max(0, 1 - (min_{c,kh,kw} A[b,c,si+kh,sj+kw] + BW[c,kh,kw,f])^(2/3))
// where A = (1-x)^1.5, BW = (1-w)^1.5.  (max over J commutes with the
// monotone-decreasing Yager combine -> tropical min-plus 3x3 conv.)

#define CIN  32
#define FOUT 32
#define KS   3
#define HW   66   // input spatial
#define SS   64   // output spatial
#define NB   4    // batch
#define JDIM (CIN * KS * KS)   // 288

__global__ __launch_bounds__(256) void yager_prep(
    const float* __restrict__ x, const float* __restrict__ w,
    float* __restrict__ A, float* __restrict__ bw, int nx, int nw)
{
    int i = blockIdx.x * 256 + threadIdx.x;
    if (i < nx) { float t = 1.0f - x[i]; A[i]  = t * sqrtf(t); }  // t^1.5
    if (i < nw) { float t = 1.0f - w[i]; bw[i] = t * sqrtf(t); }
}

__global__ __launch_bounds__(256) void yager_minconv(
    const float* __restrict__ A, const float* __restrict__ bw,
    float* __restrict__ out)
{
    const int col = threadIdx.x;                                   // 0..63 (one wave = one row)
    const int fg  = __builtin_amdgcn_readfirstlane(threadIdx.y);   // 0..3, wave-uniform -> SGPR
    const int row = blockIdx.x & (SS - 1);
    const int b   = blockIdx.x >> 6;

    const float* __restrict__ bwfg = bw + fg * 8;                  // uniform -> s_load path
    const float* __restrict__ Ab   = A + ((size_t)(b * CIN) * HW + row) * HW + col;

    float m[8];
#pragma unroll
    for (int f = 0; f < 8; ++f) m[f] = 3.0f;   // > max possible sum (a+b <= 2)

#pragma unroll 2
    for (int c = 0; c < CIN; ++c) {
        const float* Ac  = Ab + c * HW * HW;
        const float* bwc = bwfg + c * (KS * KS) * FOUT;
#pragma unroll
        for (int kh = 0; kh < KS; ++kh) {
#pragma unroll
            for (int kw = 0; kw < KS; ++kw) {
                const float a = Ac[kh * HW + kw];                  // per-lane, L1-hit
                const float* bwr = bwc + (kh * KS + kw) * FOUT;    // wave-uniform
#pragma unroll
                for (int f = 0; f < 8; ++f)
                    m[f] = fminf(m[f], a + bwr[f]);
            }
        }
    }

    float* op = out + (((size_t)b * FOUT + fg * 8) * SS + row) * SS + col;
#pragma unroll
    for (int f = 0; f < 8; ++f) {
        // m in (0,2]; m^(2/3) = exp2((2/3)*log2(m))
        float r = 1.0f - exp2f(0.6666666667f * log2f(m[f]));
        op[(size_t)f * SS * SS] = fmaxf(r, 0.0f);
    }
}

// Fallback if workspace is too small: fuse everything, BW staged in LDS.
__global__ __launch_bounds__(256) void yager_fused(
    const float* __restrict__ x, const float* __restrict__ w,
    float* __restrict__ out)
{
    __shared__ float bws[JDIM * FOUT];   // 36 KB
    for (int i = threadIdx.y * 64 + threadIdx.x; i < JDIM * FOUT; i += 256) {
        float t = 1.0f - w[i];
        bws[i] = t * sqrtf(t);
    }
    __syncthreads();

    const int col = threadIdx.x;
    const int fg  = threadIdx.y;
    const int row = blockIdx.x & (SS - 1);
    const int b   = blockIdx.x >> 6;

    const float* xb = x + ((size_t)(b * CIN) * HW + row) * HW + col;
    float m[8];
#pragma unroll
    for (int f = 0; f < 8; ++f) m[f] = 3.0f;

    for (int c = 0; c < CIN; ++c) {
        const float* xc = xb + c * HW * HW;
        const float* bc = bws + c * (KS * KS) * FOUT + fg * 8;
#pragma unroll
        for (int kh = 0; kh < KS; ++kh) {
#pragma unroll
            for (int kw = 0; kw < KS; ++kw) {
                float t = 1.0f - xc[kh * HW + kw];
                const float a = t * sqrtf(t);
                const float* br = bc + (kh * KS + kw) * FOUT;
#pragma unroll
                for (int f = 0; f < 8; ++f)
                    m[f] = fminf(m[f], a + br[f]);
            }
        }
    }

    float* op = out + (((size_t)b * FOUT + fg * 8) * SS + row) * SS + col;
#pragma unroll
    for (int f = 0; f < 8; ++f) {
        float r = 1.0f - exp2f(0.6666666667f * log2f(m[f]));
        op[(size_t)f * SS * SS] = fmaxf(r, 0.0f);
    }
}

extern "C" void kernel_launch(void* const* d_in, const int* in_sizes, int n_in,
                              void* d_out, int out_size, void* d_ws, size_t ws_size,
                              hipStream_t stream)
{
    const float* x = (const float*)d_in[0];   // [4,32,66,66] f32
    const float* w = (const float*)d_in[1];   // [288,32] f32
    float* out = (float*)d_out;               // [4,32,64,64] f32

    const int nA = NB * CIN * HW * HW;   // 557568
    const int nW = JDIM * FOUT;          // 9216
    const size_t need = (size_t)(nA + nW) * sizeof(float);

    dim3 blk(64, 4);
    dim3 grd(NB * SS);   // 256 blocks

    if (ws_size >= need) {
        float* A  = (float*)d_ws;
        float* bw = A + nA;
        yager_prep<<<(nA + 255) / 256, 256, 0, stream>>>(x, w, A, bw, nA, nW);
        yager_minconv<<<grd, blk, 0, stream>>>(A, bw, out);
    } else {
        yager_fused<<<grd, blk, 0, stream>>>(x, w, out);
    }
}

// Round 2
// 23.341 us; speedup vs baseline: 3.1809x; 3.1809x over previous
//
#include <hip/hip_runtime.h>
#include <math.h>

// MaxYager2d: out[b,f,si,sj] = max(0, 1 - (min_{c,kh,kw} A[b,c,si+kh,sj+kw] + BW[c,kh,kw,f])^(2/3))
// where A = (1-x)^1.5, BW = (1-w)^1.5.  Max over J commutes with the
// monotone-decreasing Yager combine -> tropical min-plus 3x3 conv.

#define CIN  32
#define FOUT 32
#define KS   3
#define HW   66   // input spatial
#define SS   64   // output spatial
#define NB   4    // batch
#define JDIM (CIN * KS * KS)   // 288

// prep: A = (1-x)^1.5 ; bwT[f][c*9+kh*3+kw] = (1-w[(c*9+kh*3+kw)*32+f])^1.5
__global__ __launch_bounds__(256) void yager_prep(
    const float* __restrict__ x, const float* __restrict__ w,
    float* __restrict__ A, float* __restrict__ bwT, int nx, int nw)
{
    int i = blockIdx.x * 256 + threadIdx.x;
    if (i < nx) { float t = 1.0f - x[i]; A[i] = t * sqrtf(t); }   // t^1.5
    if (i < nw) {
        float t = 1.0f - w[i];
        int f = i & (FOUT - 1);
        int j = i >> 5;
        bwT[f * JDIM + j] = t * sqrtf(t);
    }
}

// 2 f per thread, 4 waves/block, 1024 blocks -> 4096 waves (4/SIMD).
__global__ __launch_bounds__(256, 4) void yager_minconv(
    const float* __restrict__ A, const float* __restrict__ bwT,
    float* __restrict__ out)
{
    const int col  = threadIdx.x;                       // 0..63
    const int bidx = blockIdx.x;                        // 0..1023
    const int fblk = bidx & 3;                          // 4 f-blocks of 8
    const int rowb = bidx >> 2;
    const int row  = rowb & (SS - 1);
    const int b    = rowb >> 6;
    // wave-uniform f base (2 f per thread)
    const int f0 = __builtin_amdgcn_readfirstlane(fblk * 8 + threadIdx.y * 2);

    const float* __restrict__ Ab  = A + ((size_t)(b * CIN) * HW + row) * HW + col;
    const float* __restrict__ bw0 = bwT + (size_t)f0 * JDIM;        // uniform -> s_load
    const float* __restrict__ bw1 = bw0 + JDIM;

    float m0 = 3.0f, m1 = 3.0f;   // > max possible sum (a+b <= 2)

#pragma unroll 8
    for (int c = 0; c < CIN; ++c) {
        const float* Ac = Ab + (size_t)c * HW * HW;
        float a[KS * KS];
#pragma unroll
        for (int kh = 0; kh < KS; ++kh)
#pragma unroll
            for (int kw = 0; kw < KS; ++kw)
                a[kh * KS + kw] = Ac[kh * HW + kw];
#pragma unroll
        for (int t = 0; t < KS * KS; ++t) {
            const float b0 = bw0[c * KS * KS + t];
            const float b1 = bw1[c * KS * KS + t];
            m0 = fminf(m0, a[t] + b0);
            m1 = fminf(m1, a[t] + b1);
        }
    }

    float* op = out + (((size_t)b * FOUT + f0) * SS + row) * SS + col;
    {
        float r0 = 1.0f - exp2f(0.6666666667f * log2f(m0));
        float r1 = 1.0f - exp2f(0.6666666667f * log2f(m1));
        op[0]       = fmaxf(r0, 0.0f);
        op[SS * SS] = fmaxf(r1, 0.0f);
    }
}

// Fallback if workspace is too small: fused single kernel (known-good, r1).
__global__ __launch_bounds__(256) void yager_fused(
    const float* __restrict__ x, const float* __restrict__ w,
    float* __restrict__ out)
{
    __shared__ float bws[JDIM * FOUT];   // 36 KB
    for (int i = threadIdx.y * 64 + threadIdx.x; i < JDIM * FOUT; i += 256) {
        float t = 1.0f - w[i];
        bws[i] = t * sqrtf(t);
    }
    __syncthreads();

    const int col = threadIdx.x;
    const int fg  = threadIdx.y;
    const int row = blockIdx.x & (SS - 1);
    const int b   = blockIdx.x >> 6;

    const float* xb = x + ((size_t)(b * CIN) * HW + row) * HW + col;
    float m[8];
#pragma unroll
    for (int f = 0; f < 8; ++f) m[f] = 3.0f;

    for (int c = 0; c < CIN; ++c) {
        const float* xc = xb + (size_t)c * HW * HW;
        const float* bc = bws + c * (KS * KS) * FOUT + fg * 8;
#pragma unroll
        for (int kh = 0; kh < KS; ++kh)
#pragma unroll
            for (int kw = 0; kw < KS; ++kw) {
                float t = 1.0f - xc[kh * HW + kw];
                const float a = t * sqrtf(t);
                const float* br = bc + (kh * KS + kw) * FOUT;
#pragma unroll
                for (int f = 0; f < 8; ++f)
                    m[f] = fminf(m[f], a + br[f]);
            }
    }

    float* op = out + (((size_t)b * FOUT + fg * 8) * SS + row) * SS + col;
#pragma unroll
    for (int f = 0; f < 8; ++f) {
        float r = 1.0f - exp2f(0.6666666667f * log2f(m[f]));
        op[(size_t)f * SS * SS] = fmaxf(r, 0.0f);
    }
}

extern "C" void kernel_launch(void* const* d_in, const int* in_sizes, int n_in,
                              void* d_out, int out_size, void* d_ws, size_t ws_size,
                              hipStream_t stream)
{
    const float* x = (const float*)d_in[0];   // [4,32,66,66] f32
    const float* w = (const float*)d_in[1];   // [288,32] f32
    float* out = (float*)d_out;               // [4,32,64,64] f32

    const int nA = NB * CIN * HW * HW;   // 557568
    const int nW = JDIM * FOUT;          // 9216
    const size_t need = (size_t)(nA + nW) * sizeof(float);

    if (ws_size >= need) {
        float* A   = (float*)d_ws;
        float* bwT = A + nA;
        yager_prep<<<(nA + 255) / 256, 256, 0, stream>>>(x, w, A, bwT, nA, nW);
        dim3 blk(64, 4);
        dim3 grd(NB * SS * 4);   // 1024 blocks, 4096 waves
        yager_minconv<<<grd, blk, 0, stream>>>(A, bwT, out);
    } else {
        dim3 blk(64, 4);
        dim3 grd(NB * SS);
        yager_fused<<<grd, blk, 0, stream>>>(x, w, out);
    }
}

// Round 3
// 19.718 us; speedup vs baseline: 3.7655x; 1.1838x over previous
//
#include <hip/hip_runtime.h>
#include <math.h>

// MaxYager2d: out[b,f,si,sj] = max(0, 1 - (min_{c,kh,kw} A[b,c,si+kh,sj+kw] + BW[c,kh,kw,f])^(2/3))
// where A = (1-x)^1.5, BW = (1-w)^1.5.  Max over J commutes with the
// monotone-decreasing Yager combine -> tropical min-plus 3x3 conv.
//
// r3: one (b,row) per 1024-thread block; A-window (3x66x32) computed from x
// into LDS during staging (no A workspace, no big prep); 16 waves x 2 f each;
// bw pre-transposed [F][J] in ws so per-wave bw taps are wave-uniform s_loads.

#define CIN  32
#define FOUT 32
#define KS   3
#define HW   66   // input spatial
#define SS   64   // output spatial
#define NB   4    // batch
#define JDIM (CIN * KS * KS)   // 288
#define LDW  68   // padded LDS row width (need 67, pad to 68)

__global__ __launch_bounds__(256) void yager_prep_bw(
    const float* __restrict__ w, float* __restrict__ bwT)
{
    int i = blockIdx.x * 256 + threadIdx.x;
    if (i < JDIM * FOUT) {
        float t = 1.0f - w[i];
        int f = i & (FOUT - 1);
        int j = i >> 5;
        bwT[f * JDIM + j] = t * sqrtf(t);   // (1-w)^1.5
    }
}

__global__ __launch_bounds__(1024) void yager_minconv(
    const float* __restrict__ x, const float* __restrict__ bwT,
    float* __restrict__ out)
{
    __shared__ float lds[CIN][KS][LDW];

    const int tid = threadIdx.x;
    const int row = blockIdx.x & (SS - 1);
    const int b   = blockIdx.x >> 6;

    // Stage 3-row window of all 32 channels, fusing A = (1-x)^1.5 = t*sqrt(t).
    // i runs over [c][kr][col]; global reads coalesced within each 66-col row.
    for (int i = tid; i < CIN * KS * HW; i += 1024) {
        int c  = i / (KS * HW);
        int r  = i - c * (KS * HW);
        int kr = r / HW;
        int cl = r - kr * HW;
        float t = 1.0f - x[((size_t)(b * CIN + c) * HW + row + kr) * HW + cl];
        lds[c][kr][cl] = t * sqrtf(t);
    }
    __syncthreads();

    const int lane = tid & 63;                                   // output col
    const int f0   = __builtin_amdgcn_readfirstlane(tid >> 6) * 2; // 0..30, uniform
    const float* __restrict__ bw0 = bwT + (size_t)f0 * JDIM;     // -> s_load
    const float* __restrict__ bw1 = bw0 + JDIM;

    float m0 = 3.0f, m1 = 3.0f;   // > max possible sum (a+b <= 2)

#pragma unroll 4
    for (int c = 0; c < CIN; ++c) {
        float a[KS][KS];
#pragma unroll
        for (int kr = 0; kr < KS; ++kr)
#pragma unroll
            for (int kw = 0; kw < KS; ++kw)
                a[kr][kw] = lds[c][kr][lane + kw];
#pragma unroll
        for (int t = 0; t < KS * KS; ++t) {
            const float av = a[t / KS][t % KS];
            m0 = fminf(m0, av + bw0[c * KS * KS + t]);
            m1 = fminf(m1, av + bw1[c * KS * KS + t]);
        }
    }

    float* op = out + (((size_t)b * FOUT + f0) * SS + row) * SS + lane;
    float r0 = 1.0f - exp2f(0.6666666667f * log2f(m0));
    float r1 = 1.0f - exp2f(0.6666666667f * log2f(m1));
    op[0]       = fmaxf(r0, 0.0f);
    op[SS * SS] = fmaxf(r1, 0.0f);
}

// Fallback if workspace is too small for bwT: fused single kernel (r1-proven).
__global__ __launch_bounds__(256) void yager_fused(
    const float* __restrict__ x, const float* __restrict__ w,
    float* __restrict__ out)
{
    __shared__ float bws[JDIM * FOUT];   // 36 KB
    for (int i = threadIdx.y * 64 + threadIdx.x; i < JDIM * FOUT; i += 256) {
        float t = 1.0f - w[i];
        bws[i] = t * sqrtf(t);
    }
    __syncthreads();

    const int col = threadIdx.x;
    const int fg  = threadIdx.y;
    const int row = blockIdx.x & (SS - 1);
    const int b   = blockIdx.x >> 6;

    const float* xb = x + ((size_t)(b * CIN) * HW + row) * HW + col;
    float m[8];
#pragma unroll
    for (int f = 0; f < 8; ++f) m[f] = 3.0f;

    for (int c = 0; c < CIN; ++c) {
        const float* xc = xb + (size_t)c * HW * HW;
        const float* bc = bws + c * (KS * KS) * FOUT + fg * 8;
#pragma unroll
        for (int kh = 0; kh < KS; ++kh)
#pragma unroll
            for (int kw = 0; kw < KS; ++kw) {
                float t = 1.0f - xc[kh * HW + kw];
                const float a = t * sqrtf(t);
                const float* br = bc + (kh * KS + kw) * FOUT;
#pragma unroll
                for (int f = 0; f < 8; ++f)
                    m[f] = fminf(m[f], a + br[f]);
            }
    }

    float* op = out + (((size_t)b * FOUT + fg * 8) * SS + row) * SS + col;
#pragma unroll
    for (int f = 0; f < 8; ++f) {
        float r = 1.0f - exp2f(0.6666666667f * log2f(m[f]));
        op[(size_t)f * SS * SS] = fmaxf(r, 0.0f);
    }
}

extern "C" void kernel_launch(void* const* d_in, const int* in_sizes, int n_in,
                              void* d_out, int out_size, void* d_ws, size_t ws_size,
                              hipStream_t stream)
{
    const float* x = (const float*)d_in[0];   // [4,32,66,66] f32
    const float* w = (const float*)d_in[1];   // [288,32] f32
    float* out = (float*)d_out;               // [4,32,64,64] f32

    const int nW = JDIM * FOUT;               // 9216
    const size_t need = (size_t)nW * sizeof(float);

    if (ws_size >= need) {
        float* bwT = (float*)d_ws;
        yager_prep_bw<<<(nW + 255) / 256, 256, 0, stream>>>(w, bwT);
        yager_minconv<<<NB * SS, 1024, 0, stream>>>(x, bwT, out);
    } else {
        dim3 blk(64, 4);
        dim3 grd(NB * SS);
        yager_fused<<<grd, blk, 0, stream>>>(x, w, out);
    }
}

// Round 5
// 18.679 us; speedup vs baseline: 3.9750x; 1.0556x over previous
//
#include <hip/hip_runtime.h>
#include <math.h>

// MaxYager2d: out[b,f,si,sj] = max(0, 1 - (min_{c,kh,kw} A[b,c,si+kh,sj+kw] + BW[c,kh,kw,f])^(2/3))
// where A = (1-x)^1.5, BW = (1-w)^1.5.  Max over J commutes with the
// monotone-decreasing Yager combine -> tropical min-plus 3x3 conv.
//
// r5: packed-f16 over channel pairs via clang-native _Float16 vectors
// (ROCm header's __hmin2 is broken). One ds_read_b32 fetches 2 channels'
// taps; inner loop is v_pk_add_f16 + v_pk_min_f16 -> both LDS and VALU
// pipe costs halve vs f32. Relative error ~5e-4 << 2e-2 threshold.

#define CIN  32
#define CP   16   // channel pairs
#define FOUT 32
#define KS   3
#define HW   66   // input spatial
#define SS   64   // output spatial
#define NB   4    // batch
#define JDIM (CIN * KS * KS)   // 288
#define LDW  68   // padded LDS row width

typedef _Float16 half2_t __attribute__((ext_vector_type(2)));

static __device__ __forceinline__ half2_t mk2(float a, float b) {
    half2_t r;
    r.x = (_Float16)a;
    r.y = (_Float16)b;
    return r;
}

// bwp[f][cp][t] = (A-style (1-w)^1.5 for channels 2cp, 2cp+1)
__global__ __launch_bounds__(256) void yager_prep_bw(
    const float* __restrict__ w, half2_t* __restrict__ bwp)
{
    int i = blockIdx.x * 256 + threadIdx.x;     // over [f][cp][t], 32*16*9 = 4608
    if (i >= FOUT * CP * 9) return;
    int f  = i / (CP * 9);
    int r  = i - f * (CP * 9);
    int cp = r / 9;
    int t  = r - cp * 9;
    float w0 = w[((2 * cp)     * 9 + t) * FOUT + f];
    float w1 = w[((2 * cp + 1) * 9 + t) * FOUT + f];
    float t0 = 1.0f - w0, t1 = 1.0f - w1;
    bwp[i] = mk2(t0 * sqrtf(t0), t1 * sqrtf(t1));   // t^1.5
}

__global__ __launch_bounds__(1024) void yager_minconv(
    const float* __restrict__ x, const half2_t* __restrict__ bwp,
    float* __restrict__ out)
{
    __shared__ half2_t ldsA[CP][KS][LDW];   // 13 KB

    const int tid = threadIdx.x;
    const int row = blockIdx.x & (SS - 1);
    const int b   = blockIdx.x >> 6;

    // Stage 3-row window, 2 channels per half2, fusing A = t*sqrt(t).
    for (int i = tid; i < CP * KS * HW; i += 1024) {
        int cp  = i / (KS * HW);
        int r   = i - cp * (KS * HW);
        int kr  = r / HW;
        int col = r - kr * HW;
        const float* xp = x + ((size_t)(b * CIN + 2 * cp) * HW + row + kr) * HW + col;
        float t0 = 1.0f - xp[0];
        float t1 = 1.0f - xp[HW * HW];
        ldsA[cp][kr][col] = mk2(t0 * sqrtf(t0), t1 * sqrtf(t1));
    }
    __syncthreads();

    const int lane = tid & 63;                                       // output col
    const int f0   = __builtin_amdgcn_readfirstlane((tid >> 6) * 2); // wave-uniform
    const half2_t* __restrict__ bw0 = bwp + (size_t)f0 * (CP * 9);   // -> s_load
    const half2_t* __restrict__ bw1 = bw0 + CP * 9;

    half2_t M0 = mk2(4.0f, 4.0f);   // > max possible sum (a+b <= 2)
    half2_t M1 = M0;

#pragma unroll 4
    for (int cp = 0; cp < CP; ++cp) {
        half2_t a[KS][KS];
#pragma unroll
        for (int kr = 0; kr < KS; ++kr)
#pragma unroll
            for (int kw = 0; kw < KS; ++kw)
                a[kr][kw] = ldsA[cp][kr][lane + kw];
#pragma unroll
        for (int t = 0; t < 9; ++t) {
            half2_t av = a[t / 3][t % 3];
            M0 = __builtin_elementwise_min(M0, (half2_t)(av + bw0[cp * 9 + t]));
            M1 = __builtin_elementwise_min(M1, (half2_t)(av + bw1[cp * 9 + t]));
        }
    }

    float m0 = fminf((float)M0.x, (float)M0.y);
    float m1 = fminf((float)M1.x, (float)M1.y);
    float r0 = 1.0f - exp2f(0.6666666667f * log2f(m0));
    float r1 = 1.0f - exp2f(0.6666666667f * log2f(m1));
    float* op = out + (((size_t)b * FOUT + f0) * SS + row) * SS + lane;
    op[0]       = fmaxf(r0, 0.0f);
    op[SS * SS] = fmaxf(r1, 0.0f);
}

// Fallback if workspace is too small for bwp: fused f32 kernel (r1-proven).
__global__ __launch_bounds__(256) void yager_fused(
    const float* __restrict__ x, const float* __restrict__ w,
    float* __restrict__ out)
{
    __shared__ float bws[JDIM * FOUT];   // 36 KB
    for (int i = threadIdx.y * 64 + threadIdx.x; i < JDIM * FOUT; i += 256) {
        float t = 1.0f - w[i];
        bws[i] = t * sqrtf(t);
    }
    __syncthreads();

    const int col = threadIdx.x;
    const int fg  = threadIdx.y;
    const int row = blockIdx.x & (SS - 1);
    const int b   = blockIdx.x >> 6;

    const float* xb = x + ((size_t)(b * CIN) * HW + row) * HW + col;
    float m[8];
#pragma unroll
    for (int f = 0; f < 8; ++f) m[f] = 3.0f;

    for (int c = 0; c < CIN; ++c) {
        const float* xc = xb + (size_t)c * HW * HW;
        const float* bc = bws + c * (KS * KS) * FOUT + fg * 8;
#pragma unroll
        for (int kh = 0; kh < KS; ++kh)
#pragma unroll
            for (int kw = 0; kw < KS; ++kw) {
                float t = 1.0f - xc[kh * HW + kw];
                const float a = t * sqrtf(t);
                const float* br = bc + (kh * KS + kw) * FOUT;
#pragma unroll
                for (int f = 0; f < 8; ++f)
                    m[f] = fminf(m[f], a + br[f]);
            }
    }

    float* op = out + (((size_t)b * FOUT + fg * 8) * SS + row) * SS + col;
#pragma unroll
    for (int f = 0; f < 8; ++f) {
        float r = 1.0f - exp2f(0.6666666667f * log2f(m[f]));
        op[(size_t)f * SS * SS] = fmaxf(r, 0.0f);
    }
}

extern "C" void kernel_launch(void* const* d_in, const int* in_sizes, int n_in,
                              void* d_out, int out_size, void* d_ws, size_t ws_size,
                              hipStream_t stream)
{
    const float* x = (const float*)d_in[0];   // [4,32,66,66] f32
    const float* w = (const float*)d_in[1];   // [288,32] f32
    float* out = (float*)d_out;               // [4,32,64,64] f32

    const int nBW = FOUT * CP * 9;            // 4608 half2
    const size_t need = (size_t)nBW * sizeof(half2_t);

    if (ws_size >= need) {
        half2_t* bwp = (half2_t*)d_ws;
        yager_prep_bw<<<(nBW + 255) / 256, 256, 0, stream>>>(w, bwp);
        yager_minconv<<<NB * SS, 1024, 0, stream>>>(x, bwp, out);
    } else {
        dim3 blk(64, 4);
        dim3 grd(NB * SS);
        yager_fused<<<grd, blk, 0, stream>>>(x, w, out);
    }
}